// Round 16
// baseline (417.015 us; speedup 1.0000x reference)
//
#include <hip/hip_runtime.h>
#include <hip/hip_cooperative_groups.h>
#include <math.h>

namespace cg = cooperative_groups;

#define NB 65536
#define EV 131072
#define NE (2*EV)
#define DM 128
#define BM 64
#define NST 10       // K tiles of 64
#define THREADS 512  // 8 waves, 1M x 8N, wave tile 64x64 = 2x2 MFMA 32x32

typedef float f32x4  __attribute__((ext_vector_type(4)));
typedef float f32x16 __attribute__((ext_vector_type(16)));
typedef int   i32x4  __attribute__((ext_vector_type(4)));
typedef int   i32x8  __attribute__((ext_vector_type(8)));
typedef unsigned long long u64;

// ---- fast transcendentals (HW ops) ----
__device__ __forceinline__ float fcos_rev(float rev) {
    float r; asm("v_cos_f32 %0, %1" : "=v"(r) : "v"(rev)); return r;
}
__device__ __forceinline__ float fexp2(float x) {
    float r; asm("v_exp_f32 %0, %1" : "=v"(r) : "v"(x)); return r;
}
__device__ __forceinline__ float frcp(float x) {
    float r; asm("v_rcp_f32 %0, %1" : "=v"(r) : "v"(x)); return r;
}
__device__ __forceinline__ float fast_cos(float arg) {   // |arg| up to ~1e6
    double rv = (double)arg * 0.15915494309189535;
    rv -= floor(rv);
    return fcos_rev((float)rv);
}
__device__ __forceinline__ float fsigmoid(float x) {
    x = fminf(fmaxf(x, -30.f), 30.f);
    float e = fexp2(-1.44269504088896f * x);
    return frcp(1.f + e);
}
__device__ __forceinline__ float ftanh_(float x) {
    x = fminf(fmaxf(x, -15.f), 15.f);
    float e = fexp2(-2.88539008177793f * x);
    return (1.f - e) * frcp(1.f + e);
}

// ---- fp8 e4m3 packing ----
#if defined(__has_builtin) && __has_builtin(__builtin_amdgcn_cvt_pk_fp8_f32)
__device__ __forceinline__ unsigned pack4_fp8(float f0, float f1, float f2, float f3) {
    int v = __builtin_amdgcn_cvt_pk_fp8_f32(f0, f1, 0, false);
    v = __builtin_amdgcn_cvt_pk_fp8_f32(f2, f3, v, true);
    return (unsigned)v;
}
#else
__device__ __forceinline__ unsigned enc1_fp8(float x) {
    unsigned u = __float_as_uint(x);
    unsigned s = (u >> 24) & 0x80u;
    float a = fabsf(x);
    if (!(a >= 0.001953125f)) return s;
    if (a > 448.f) a = 448.f;
    int e; float mf = frexpf(a, &e);
    int E = e + 6, mant;
    if (E <= 0) {
        mant = (int)(a * 512.f + 0.5f);
        if (mant > 7) return s | 0x08u;
        return s | (unsigned)mant;
    }
    mant = (int)((mf * 2.f - 1.f) * 8.f + 0.5f);
    if (mant == 8) { mant = 0; ++E; }
    if (E > 15) { E = 15; mant = 6; }
    if (E == 15 && mant == 7) mant = 6;
    return s | (unsigned)(E << 3) | (unsigned)mant;
}
__device__ __forceinline__ unsigned pack4_fp8(float f0, float f1, float f2, float f3) {
    return enc1_fp8(f0) | (enc1_fp8(f1) << 8) | (enc1_fp8(f2) << 16) | (enc1_fp8(f3) << 24);
}
#endif

// ================= device pieces =================

__device__ __forceinline__ void dev_scan(int e, const int* __restrict__ src_s,
                                         const int* __restrict__ t_s,
                                         const int* __restrict__ dst_d,
                                         const int* __restrict__ t_d,
                                         u64* __restrict__ keyarr, u64* __restrict__ lukey) {
    int g, t;
    if (e < EV) { g = src_s[e];      t = t_s[e]; }
    else        { g = dst_d[e - EV]; t = t_d[e - EV]; }
    u64 key = ((u64)(unsigned)t << 18) + (u64)(unsigned)e + 1ull;
    atomicMax(&keyarr[g], key);
    u64 lk = ((u64)(unsigned)(e + 1) << 20) | (u64)(unsigned)t;   // t < 2^20
    atomicMax(&lukey[g], lk);
}

// W' fp8 (x16), layout matching gemm's swizzled b128 pair-reads (r11-verified):
// wp8[step*32768 + col*64 + sl*8]; ck=(sl>>1)^((col>>1)&3); k0=step*64+ck*16+(sl&1)*8
__device__ __forceinline__ void dev_wbuild(int idx,
        const float* __restrict__ W_ih, const float* __restrict__ W_hh,
        const float* __restrict__ b_ih, const float* __restrict__ b_hh,
        unsigned char* __restrict__ wp8, float* __restrict__ bp) {
    int col = idx / 80, g = idx - col * 80;
    int step = g >> 3, sl = g & 7;
    int ck = ((sl >> 1) ^ ((col >> 1) & 3));
    int k0 = step * 64 + ck * 16 + (sl & 1) * 8;
    int d = col >> 2, gate = col & 3;
    float f[8];
    #pragma unroll
    for (int j = 0; j < 8; ++j) {
        int c = k0 + j;
        float v = 0.f;
        if (c < 512) {
            int row = (gate == 0) ? d : (gate == 1) ? 128 + d : (gate == 2) ? 256 + d : -1;
            if (row >= 0) v = W_ih[(size_t)row * 512 + c];
        } else {
            int ch = c - 512;
            int row = (gate == 0) ? d : (gate == 1) ? 128 + d : (gate == 3) ? 256 + d : -1;
            if (row >= 0) v = W_hh[(size_t)row * 128 + ch];
        }
        f[j] = v * 16.f;
    }
    unsigned lo = pack4_fp8(f[0], f[1], f[2], f[3]);
    unsigned hi = pack4_fp8(f[4], f[5], f[6], f[7]);
    *(u64*)(wp8 + (size_t)step * 32768 + (size_t)col * 64 + (size_t)sl * 8)
        = (u64)lo | ((u64)hi << 32);
    if (g == 0) {
        float bv = (gate == 0) ? b_ih[d] + b_hh[d]
                 : (gate == 1) ? b_ih[128 + d] + b_hh[128 + d]
                 : (gate == 2) ? b_ih[256 + d] : b_hh[256 + d];
        bp[col] = bv;
    }
}

// one 64-row fused MX-fp8 GEMM+GRU tile — r11's verified 64µs body, verbatim
__device__ void dev_gemm_tile(char* smem, int tid, int m0,
    const float* __restrict__ memory, const int* __restrict__ last_update,
    const int* __restrict__ src_s, const int* __restrict__ dst_s,
    const int* __restrict__ t_s, const float* __restrict__ raw_s,
    const int* __restrict__ src_d, const int* __restrict__ dst_d,
    const int* __restrict__ t_d, const float* __restrict__ raw_d,
    const float* __restrict__ w_time, const float* __restrict__ b_time,
    const unsigned char* __restrict__ wp8, const float* __restrict__ bp,
    const u64* __restrict__ keyarr, const u64* __restrict__ lukey,
    float* __restrict__ out_mem, float* __restrict__ out_lu)
{
    unsigned char* sA = (unsigned char*)smem;
    unsigned char* sB = (unsigned char*)(smem + 8192);
    float* sW = (float*)(smem + 73728);
    float* sBt= (float*)(smem + 74240);

    const int ln = tid & 63, wn = tid >> 6;
    const int lg = ln >> 5;

    __syncthreads();   // previous tile's epilogue scratch (overlays sA/sB) is done
    if (tid < DM) { sW[tid] = w_time[tid]; sBt[tid] = b_time[tid]; }

    // ---- per-thread decode ----
    const int ar = tid >> 3, ac = tid & 7;
    const int m  = m0 + ar;
    const u64 kk = keyarr[m];
    const int rv = (kk != 0ull);
    int a_ = 0, b_ = 0, t_ = 0;
    const float* pR = raw_s;
    if (kk) {
        int e = (int)((kk - 1ull) & (u64)(NE - 1));
        if (e < EV) { a_ = src_s[e]; b_ = dst_s[e]; t_ = t_s[e]; pR = raw_s + (size_t)e * DM; }
        else { int e2 = e - EV; a_ = dst_d[e2]; b_ = src_d[e2]; t_ = t_d[e2]; pR = raw_d + (size_t)e2 * DM; }
    }
    const float rt = rv ? (float)(t_ - last_update[a_]) : 0.f;
    const float* pA = memory + (size_t)a_ * DM;
    const float* pB = memory + (size_t)b_ * DM;
    const float* pH = memory + (size_t)m  * DM;

    float4 pv0, pv1;
    auto PREF_A = [&](int step) {
        int seg = step >> 1;
        if (seg == 3) return;
        const float* base = (seg == 0) ? pA : (seg == 1) ? pB : (seg == 2) ? pR : pH;
        int off = ((step & 1) << 6) + (ac << 3);
        pv0 = *(const float4*)(base + off);
        pv1 = *(const float4*)(base + off + 4);
    };
    auto STAGE_B = [&](int step, int buf) {
        const unsigned char* src = wp8 + (size_t)step * 32768 + (size_t)tid * 16;
        unsigned char* dst = sB + (size_t)buf * 32768 + (size_t)tid * 16;
        #pragma unroll
        for (int i = 0; i < 4; ++i)
            __builtin_amdgcn_global_load_lds(
                (const __attribute__((address_space(1))) void*)(src + i * 8192),
                (__attribute__((address_space(3))) void*)(dst + i * 8192), 16, 0, 0);
    };
    auto WRITE_A = [&](int step, int buf) {
        int seg = step >> 1;
        float f0, f1, f2, f3, f4, f5, f6, f7;
        if (seg == 3) {
            int coff = ((step & 1) << 6) + (ac << 3);
            f0 = fast_cos(__fadd_rn(__fmul_rn(rt, sW[coff+0]), sBt[coff+0]));
            f1 = fast_cos(__fadd_rn(__fmul_rn(rt, sW[coff+1]), sBt[coff+1]));
            f2 = fast_cos(__fadd_rn(__fmul_rn(rt, sW[coff+2]), sBt[coff+2]));
            f3 = fast_cos(__fadd_rn(__fmul_rn(rt, sW[coff+3]), sBt[coff+3]));
            f4 = fast_cos(__fadd_rn(__fmul_rn(rt, sW[coff+4]), sBt[coff+4]));
            f5 = fast_cos(__fadd_rn(__fmul_rn(rt, sW[coff+5]), sBt[coff+5]));
            f6 = fast_cos(__fadd_rn(__fmul_rn(rt, sW[coff+6]), sBt[coff+6]));
            f7 = fast_cos(__fadd_rn(__fmul_rn(rt, sW[coff+7]), sBt[coff+7]));
        } else {
            f0 = pv0.x; f1 = pv0.y; f2 = pv0.z; f3 = pv0.w;
            f4 = pv1.x; f5 = pv1.y; f6 = pv1.z; f7 = pv1.w;
        }
        if (seg < 4 && !rv) { f0=f1=f2=f3=f4=f5=f6=f7 = 0.f; }
        unsigned lo = pack4_fp8(f0, f1, f2, f3);
        unsigned hi = pack4_fp8(f4, f5, f6, f7);
        u64 q = (u64)lo | ((u64)hi << 32);
        *(u64*)(sA + buf * 4096 + ar * 64
                + (((ac >> 1) ^ ((ar >> 1) & 3)) << 4) + ((ac & 1) << 3)) = q;
    };

    f32x16 acc[2][2];
    #pragma unroll
    for (int mf = 0; mf < 2; ++mf)
        #pragma unroll
        for (int nf = 0; nf < 2; ++nf)
            #pragma unroll
            for (int j = 0; j < 16; ++j) acc[mf][nf][j] = 0.f;

    // ---- pipeline prologue ----
    PREF_A(0);
    WRITE_A(0, 0);
    STAGE_B(0, 0);
    PREF_A(1);
    asm volatile("s_waitcnt vmcnt(2) lgkmcnt(0)" ::: "memory");
    __builtin_amdgcn_sched_barrier(0);
    __builtin_amdgcn_s_barrier();

    #pragma unroll
    for (int k = 0; k < NST; ++k) {
        const int cur = k & 1, nxt = cur ^ 1;

        if (k < NST - 1) {
            WRITE_A(k + 1, nxt);
            __builtin_amdgcn_sched_barrier(0);
            STAGE_B(k + 1, nxt);
            __builtin_amdgcn_sched_barrier(0);
        }

        i32x8 af[2], bf[2];
        #pragma unroll
        for (int mf = 0; mf < 2; ++mf) {
            int r = mf * 32 + (ln & 31), sw = (r >> 1) & 3;
            i32x4 q0 = *(const i32x4*)(sA + cur * 4096 + r * 64 + (((2*lg+0) ^ sw) << 4));
            i32x4 q1 = *(const i32x4*)(sA + cur * 4096 + r * 64 + (((2*lg+1) ^ sw) << 4));
            af[mf] = (i32x8){q0.x,q0.y,q0.z,q0.w, q1.x,q1.y,q1.z,q1.w};
        }
        #pragma unroll
        for (int nf = 0; nf < 2; ++nf) {
            int c = wn * 64 + nf * 32 + (ln & 31), sw = (c >> 1) & 3;
            i32x4 q0 = *(const i32x4*)(sB + cur * 32768 + c * 64 + (((2*lg+0) ^ sw) << 4));
            i32x4 q1 = *(const i32x4*)(sB + cur * 32768 + c * 64 + (((2*lg+1) ^ sw) << 4));
            bf[nf] = (i32x8){q0.x,q0.y,q0.z,q0.w, q1.x,q1.y,q1.z,q1.w};
        }
        __builtin_amdgcn_sched_barrier(0);

        const bool pf = (k + 2 <= NST - 1) && (((k + 2) >> 1) != 3);
        if (pf) PREF_A(k + 2);
        __builtin_amdgcn_sched_barrier(0);

        __builtin_amdgcn_s_setprio(1);
        #pragma unroll
        for (int mf = 0; mf < 2; ++mf)
            #pragma unroll
            for (int nf = 0; nf < 2; ++nf)
                acc[mf][nf] = __builtin_amdgcn_mfma_scale_f32_32x32x64_f8f6f4(
                    af[mf], bf[nf], acc[mf][nf], 0, 0, 0, 127, 0, 127);
        __builtin_amdgcn_s_setprio(0);

        if (k < NST - 1) {
            __builtin_amdgcn_sched_barrier(0);
            if (pf) asm volatile("s_waitcnt vmcnt(2) lgkmcnt(0)" ::: "memory");
            else    asm volatile("s_waitcnt vmcnt(0) lgkmcnt(0)" ::: "memory");
            __builtin_amdgcn_sched_barrier(0);
            __builtin_amdgcn_s_barrier();
        }
    }

    // ---- new_last_update (folded) ----
    if (tid < BM) {
        u64 lk = lukey[m0 + tid];
        out_lu[m0 + tid] = lk ? (float)(unsigned)(lk & 0xFFFFFull)
                              : (float)last_update[m0 + tid];
    }
    __syncthreads();    // frag reads done; per-wave scratch overlays sA/sB

    // ---- epilogue: per-wave LDS transpose (32x32 C layout), fused GRU ----
    float* ep = (float*)(smem + wn * 8704);           // [32][68] f32
    const int erow = ln >> 1, half = ln & 1;
    const int d0 = wn * 16 + half * 8;
    const float ds = 0.0625f;                          // 1/16 (W scale)

    #pragma unroll
    for (int mf = 0; mf < 2; ++mf) {
        #pragma unroll
        for (int nf = 0; nf < 2; ++nf)
            #pragma unroll
            for (int reg = 0; reg < 16; ++reg) {
                int r32 = (reg & 3) + 8 * (reg >> 2) + 4 * lg;   // 0..31
                ep[r32 * 68 + nf * 32 + (ln & 31)] = acc[mf][nf][reg] * ds;
            }
        asm volatile("s_waitcnt lgkmcnt(0)" ::: "memory");

        const int gm = m0 + mf * 32 + erow;
        const float* gr = ep + erow * 68 + half * 32;
        float res[8];
        f32x4 h0 = *(const f32x4*)(memory + (size_t)gm * DM + d0);
        f32x4 h1 = *(const f32x4*)(memory + (size_t)gm * DM + d0 + 4);
        #pragma unroll
        for (int q = 0; q < 8; ++q) {
            f32x4 g  = *(const f32x4*)(gr + q * 4);
            f32x4 bb = *(const f32x4*)(bp + (d0 + q) * 4);
            float rg = fsigmoid(g.x + bb.x);
            float zg = fsigmoid(g.y + bb.y);
            float ng = ftanh_(g.z + bb.z + rg * (g.w + bb.w));
            float hh = (q < 4) ? ((const float*)&h0)[q] : ((const float*)&h1)[q - 4];
            res[q] = (1.f - zg) * ng + zg * hh;
        }
        *(f32x4*)(out_mem + (size_t)gm * DM + d0)     = *(const f32x4*)res;
        *(f32x4*)(out_mem + (size_t)gm * DM + d0 + 4) = *(const f32x4*)(res + 4);
        if (mf == 0) asm volatile("s_waitcnt lgkmcnt(0)" ::: "memory");
    }
}

// ================= kernels =================

struct KArgs {
    const float* memory; const int* last_update;
    const int* src_s; const int* dst_s; const int* t_s; const float* raw_s;
    const int* src_d; const int* dst_d; const int* t_d; const float* raw_d;
    const float* w_time; const float* b_time;
    const float* W_ih; const float* W_hh; const float* b_ih; const float* b_hh;
    u64* keyarr; u64* lukey; unsigned char* wp8; float* bp;
    float* out_mem; float* out_lu;
};

// cooperative mega-kernel: zero -> sync -> scan + W-build -> sync -> gemm x2 tiles
__global__ __launch_bounds__(THREADS, 4) void mega_k(KArgs a) {
    __shared__ __align__(16) char smem[74752];
    cg::grid_group grid = cg::this_grid();
    const int tid  = threadIdx.x;
    const int gtid = blockIdx.x * THREADS + tid;

    ((unsigned*)a.keyarr)[gtid] = 0u;     // keyarr+lukey contiguous 1MB = 262144 u32
    grid.sync();

    dev_scan(gtid, a.src_s, a.t_s, a.dst_d, a.t_d, a.keyarr, a.lukey);
    if (blockIdx.x < 40) {
        int i0 = gtid * 2;                // 40 blocks x 512 thr x 2 = 40960 granules
        dev_wbuild(i0,     a.W_ih, a.W_hh, a.b_ih, a.b_hh, a.wp8, a.bp);
        dev_wbuild(i0 + 1, a.W_ih, a.W_hh, a.b_ih, a.b_hh, a.wp8, a.bp);
    }
    grid.sync();

    #pragma unroll 1
    for (int rep = 0; rep < 2; ++rep)
        dev_gemm_tile(smem, tid, (blockIdx.x + rep * 512) * BM,
            a.memory, a.last_update, a.src_s, a.dst_s, a.t_s, a.raw_s,
            a.src_d, a.dst_d, a.t_d, a.raw_d, a.w_time, a.b_time,
            a.wp8, a.bp, a.keyarr, a.lukey, a.out_mem, a.out_lu);
}

// ---- fallback path (non-cooperative), r11-equivalent ----
__global__ void zero2_k(unsigned* __restrict__ p) {
    p[blockIdx.x * THREADS + threadIdx.x] = 0u;
}
__global__ void prep2_k(KArgs a) {
    int bid = blockIdx.x;
    if (bid < 512) {
        dev_scan(bid * THREADS + threadIdx.x, a.src_s, a.t_s, a.dst_d, a.t_d,
                 a.keyarr, a.lukey);
        return;
    }
    int idx = (bid - 512) * THREADS + threadIdx.x;   // [0, 20480)
    dev_wbuild(idx * 2,     a.W_ih, a.W_hh, a.b_ih, a.b_hh, a.wp8, a.bp);
    dev_wbuild(idx * 2 + 1, a.W_ih, a.W_hh, a.b_ih, a.b_hh, a.wp8, a.bp);
}
__global__ __launch_bounds__(THREADS, 4) void gemm2_k(KArgs a) {
    __shared__ __align__(16) char smem[74752];
    dev_gemm_tile(smem, threadIdx.x, blockIdx.x * BM,
        a.memory, a.last_update, a.src_s, a.dst_s, a.t_s, a.raw_s,
        a.src_d, a.dst_d, a.t_d, a.raw_d, a.w_time, a.b_time,
        a.wp8, a.bp, a.keyarr, a.lukey, a.out_mem, a.out_lu);
}

extern "C" void kernel_launch(void* const* d_in, const int* in_sizes, int n_in,
                              void* d_out, int out_size, void* d_ws, size_t ws_size,
                              hipStream_t stream) {
    char* ws = (char*)d_ws;
    float* out_mem = (float*)d_out;

    KArgs ka;
    ka.memory      = (const float*)d_in[0];
    ka.last_update = (const int*)d_in[1];
    ka.src_s       = (const int*)d_in[3];
    ka.dst_s       = (const int*)d_in[4];
    ka.t_s         = (const int*)d_in[5];
    ka.raw_s       = (const float*)d_in[6];
    ka.src_d       = (const int*)d_in[7];
    ka.dst_d       = (const int*)d_in[8];
    ka.t_d         = (const int*)d_in[9];
    ka.raw_d       = (const float*)d_in[10];
    ka.w_time      = (const float*)d_in[11];
    ka.b_time      = (const float*)d_in[12];
    ka.W_ih        = (const float*)d_in[13];
    ka.W_hh        = (const float*)d_in[14];
    ka.b_ih        = (const float*)d_in[15];
    ka.b_hh        = (const float*)d_in[16];
    ka.keyarr      = (u64*)ws;                              // 512KB
    ka.lukey       = (u64*)(ws + 524288);                   // 512KB (contiguous w/ keyarr)
    ka.wp8         = (unsigned char*)(ws + 1048576);        // 320KB
    ka.bp          = (float*)(ws + 1376256);                // 2KB
    ka.out_mem     = out_mem;
    ka.out_lu      = out_mem + (size_t)NB * DM;

    void* params[] = { (void*)&ka };
    hipError_t err = hipLaunchCooperativeKernel((const void*)mega_k,
                                                dim3(512), dim3(THREADS),
                                                params, 0, stream);
    if (err != hipSuccess) {
        // fallback: r11-equivalent 3-dispatch pipeline
        zero2_k<<<512, THREADS, 0, stream>>>((unsigned*)ws);
        prep2_k<<<552, THREADS, 0, stream>>>(ka);
        gemm2_k<<<NB / BM, THREADS, 0, stream>>>(ka);
    }
}